// Round 2
// baseline (296.326 us; speedup 1.0000x reference)
//
#include <hip/hip_runtime.h>
#include <hip/hip_bf16.h>

// Problem constants
#define N_ 32
#define T_ 1024
#define E_ 64
#define H_ 8
#define D_ 8
#define NT_H (N_*T_*H_)      // 262144
#define NHTD (N_*H_*T_*D_)   // 2097152 floats per tensor

// ---------------------------------------------------------------------------
// Kernel 1: fused per-head projections  v,k,q -> vp,kp,qp  (layout [N,H,T,D] fp32)
// in: [N,T,H*D] fp32 ; W: [D,D] fp32 row-major (out,in); y[d] = sum_e x[e]*W[d][e]
// One thread per (n,t,h): reads 8 floats, does 3 x 8x8 matvec, writes 3 x 8 floats.
// ---------------------------------------------------------------------------
__global__ __launch_bounds__(256) void proj_kernel(
    const float* __restrict__ vals,
    const float* __restrict__ keys,
    const float* __restrict__ qrys,
    const float* __restrict__ Wv,
    const float* __restrict__ Wk,
    const float* __restrict__ Wq,
    float* __restrict__ vp, float* __restrict__ kp, float* __restrict__ qp)
{
    __shared__ float Wvs[64], Wks[64], Wqs[64];
    const int tid = threadIdx.x;
    if (tid < 64)        Wvs[tid]       = Wv[tid];
    else if (tid < 128)  Wks[tid - 64]  = Wk[tid - 64];
    else if (tid < 192)  Wqs[tid - 128] = Wq[tid - 128];
    __syncthreads();

    const int idx = blockIdx.x * 256 + tid;   // (n*T + t)*H + h
    const int h  = idx & (H_ - 1);
    const int nt = idx >> 3;                  // n*T + t
    const int t  = nt & (T_ - 1);
    const int n  = nt >> 10;
    const int out_off = (((n * H_ + h) * T_) + t) * D_;   // floats

    const float4 xv0 = ((const float4*)vals)[idx*2], xv1 = ((const float4*)vals)[idx*2+1];
    const float4 xk0 = ((const float4*)keys)[idx*2], xk1 = ((const float4*)keys)[idx*2+1];
    const float4 xq0 = ((const float4*)qrys)[idx*2], xq1 = ((const float4*)qrys)[idx*2+1];

    float x[8], o[8];
    // ---- values ----
    x[0]=xv0.x; x[1]=xv0.y; x[2]=xv0.z; x[3]=xv0.w;
    x[4]=xv1.x; x[5]=xv1.y; x[6]=xv1.z; x[7]=xv1.w;
    #pragma unroll
    for (int d = 0; d < 8; ++d) {
        float a = 0.f;
        #pragma unroll
        for (int e = 0; e < 8; ++e) a += x[e] * Wvs[d*8 + e];
        o[d] = a;
    }
    ((float4*)(vp + out_off))[0] = make_float4(o[0], o[1], o[2], o[3]);
    ((float4*)(vp + out_off))[1] = make_float4(o[4], o[5], o[6], o[7]);
    // ---- keys ----
    x[0]=xk0.x; x[1]=xk0.y; x[2]=xk0.z; x[3]=xk0.w;
    x[4]=xk1.x; x[5]=xk1.y; x[6]=xk1.z; x[7]=xk1.w;
    #pragma unroll
    for (int d = 0; d < 8; ++d) {
        float a = 0.f;
        #pragma unroll
        for (int e = 0; e < 8; ++e) a += x[e] * Wks[d*8 + e];
        o[d] = a;
    }
    ((float4*)(kp + out_off))[0] = make_float4(o[0], o[1], o[2], o[3]);
    ((float4*)(kp + out_off))[1] = make_float4(o[4], o[5], o[6], o[7]);
    // ---- query ----
    x[0]=xq0.x; x[1]=xq0.y; x[2]=xq0.z; x[3]=xq0.w;
    x[4]=xq1.x; x[5]=xq1.y; x[6]=xq1.z; x[7]=xq1.w;
    #pragma unroll
    for (int d = 0; d < 8; ++d) {
        float a = 0.f;
        #pragma unroll
        for (int e = 0; e < 8; ++e) a += x[e] * Wqs[d*8 + e];
        o[d] = a;
    }
    ((float4*)(qp + out_off))[0] = make_float4(o[0], o[1], o[2], o[3]);
    ((float4*)(qp + out_off))[1] = make_float4(o[4], o[5], o[6], o[7]);
}

// ---------------------------------------------------------------------------
// Kernel 2: attention. One thread = one query row of one (n,h).
// Logits clipped to [-5,5] -> exp cannot overflow -> single-pass softmax
// (running sum + weighted V accumulate), no max subtraction needed.
// grid = (T/256, N*H), block = 256.
// ---------------------------------------------------------------------------
#define KCHUNK 256
__global__ __launch_bounds__(256) void attn_kernel(
    const float* __restrict__ qp, const float* __restrict__ kp,
    const float* __restrict__ vp, float* __restrict__ attn)
{
    __shared__ float4 Ks[KCHUNK * 2];   // 8 KB
    __shared__ float4 Vs[KCHUNK * 2];   // 8 KB
    const int nh = blockIdx.y;                       // n*H + h
    const int q  = blockIdx.x * 256 + threadIdx.x;   // 0..1023
    const int n  = nh >> 3;
    const int h  = nh & 7;
    const float4* __restrict__ qb = (const float4*)(qp + nh * T_ * D_);
    const float4* __restrict__ kb = (const float4*)(kp + nh * T_ * D_);
    const float4* __restrict__ vb = (const float4*)(vp + nh * T_ * D_);

    const float scale = 0.125f;   // 1/sqrt(E)=1/8
    float4 q0 = qb[q*2], q1 = qb[q*2 + 1];
    q0.x *= scale; q0.y *= scale; q0.z *= scale; q0.w *= scale;
    q1.x *= scale; q1.y *= scale; q1.z *= scale; q1.w *= scale;

    float4 a0 = make_float4(0.f,0.f,0.f,0.f);
    float4 a1 = make_float4(0.f,0.f,0.f,0.f);
    float s = 0.f;

    for (int c = 0; c < T_ / KCHUNK; ++c) {
        const int base = c * KCHUNK * 2;
        Ks[threadIdx.x*2]     = kb[base + threadIdx.x*2];
        Ks[threadIdx.x*2 + 1] = kb[base + threadIdx.x*2 + 1];
        Vs[threadIdx.x*2]     = vb[base + threadIdx.x*2];
        Vs[threadIdx.x*2 + 1] = vb[base + threadIdx.x*2 + 1];
        __syncthreads();
        #pragma unroll 4
        for (int kk = 0; kk < KCHUNK; ++kk) {
            const float4 k0 = Ks[kk*2], k1 = Ks[kk*2 + 1];
            float d = q0.x*k0.x + q0.y*k0.y + q0.z*k0.z + q0.w*k0.w
                    + q1.x*k1.x + q1.y*k1.y + q1.z*k1.z + q1.w*k1.w;
            d = fminf(fmaxf(d, -5.f), 5.f);
            const float w = __expf(d);
            s += w;
            const float4 v0 = Vs[kk*2], v1 = Vs[kk*2 + 1];
            a0.x += w*v0.x; a0.y += w*v0.y; a0.z += w*v0.z; a0.w += w*v0.w;
            a1.x += w*v1.x; a1.y += w*v1.y; a1.z += w*v1.z; a1.w += w*v1.w;
        }
        __syncthreads();
    }
    const float inv = 1.f / s;
    a0.x *= inv; a0.y *= inv; a0.z *= inv; a0.w *= inv;
    a1.x *= inv; a1.y *= inv; a1.z *= inv; a1.w *= inv;
    // write [N,T,H,D] (== [N,T,E] flat)
    float4* ob = (float4*)(attn + ((n * T_ + q) * H_ + h) * D_);
    ob[0] = a0; ob[1] = a1;
}

// ---------------------------------------------------------------------------
// Kernel 3: output projection  out[n,t,:] = attn[n,t,:] @ Wo^T + bo  (fp32 out)
// block = 256 threads = 4 rows x 64 out-features. Wo staged in LDS, stride 65
// so lane eo reading Wo[eo][e] hits bank (eo+e)%32 -> 2-way (free).
// ---------------------------------------------------------------------------
__global__ __launch_bounds__(256) void oproj_kernel(
    const float* __restrict__ attn,
    const float* __restrict__ Wo,
    const float* __restrict__ bo,
    float* __restrict__ out)
{
    __shared__ float Wos[64 * 65];
    __shared__ float bos[64];
    __shared__ float rows[4 * 64];
    const int tid = threadIdx.x;
    #pragma unroll
    for (int i = 0; i < 16; ++i) {
        const int e = tid * 16 + i;          // 0..4095
        Wos[(e >> 6) * 65 + (e & 63)] = Wo[e];
    }
    if (tid < 64) bos[tid] = bo[tid];
    const int rowbase = blockIdx.x * 4;      // 4 rows of 64 per block
    rows[tid] = attn[rowbase * 64 + tid];
    __syncthreads();

    const int r  = tid >> 6;
    const int eo = tid & 63;
    float acc = bos[eo];
    const float* __restrict__ wrow = &Wos[eo * 65];
    const float* __restrict__ xrow = &rows[r * 64];
    #pragma unroll
    for (int e = 0; e < 64; ++e) acc += xrow[e] * wrow[e];
    out[rowbase * 64 + tid] = acc;
}

// ---------------------------------------------------------------------------
extern "C" void kernel_launch(void* const* d_in, const int* in_sizes, int n_in,
                              void* d_out, int out_size, void* d_ws, size_t ws_size,
                              hipStream_t stream)
{
    const float* vals = (const float*)d_in[0];
    const float* keys = (const float*)d_in[1];
    const float* qrys = (const float*)d_in[2];
    const float* Wv   = (const float*)d_in[3];
    const float* Wk   = (const float*)d_in[4];
    const float* Wq   = (const float*)d_in[5];
    const float* Wo   = (const float*)d_in[6];
    const float* bo   = (const float*)d_in[7];

    float* ws   = (float*)d_ws;
    float* vp   = ws;               // [N,H,T,D] fp32, 8 MB
    float* kp   = ws + NHTD;        // 8 MB
    float* qp   = ws + 2 * NHTD;    // 8 MB
    float* attn = ws + 3 * NHTD;    // [N,T,E] fp32, 8 MB

    proj_kernel<<<NT_H / 256, 256, 0, stream>>>(vals, keys, qrys, Wv, Wk, Wq, vp, kp, qp);
    attn_kernel<<<dim3(T_ / 256, N_ * H_), 256, 0, stream>>>(qp, kp, vp, attn);
    oproj_kernel<<<(N_ * T_) / 4, 256, 0, stream>>>(attn, Wo, bo, (float*)d_out);
}

// Round 3
// 249.540 us; speedup vs baseline: 1.1875x; 1.1875x over previous
//
#include <hip/hip_runtime.h>

// Problem constants
#define N_ 32
#define T_ 1024
#define E_ 64
#define H_ 8
#define D_ 8
#define KS_ 4            // key splits per (n,h)
#define KCH (T_/KS_)     // 256 keys per block
#define QPT 4            // queries per thread

#if __has_builtin(__builtin_amdgcn_exp2f)
#define EXP2(x) __builtin_amdgcn_exp2f(x)
#else
#define EXP2(x) exp2f(x)
#endif

#define LOG2E 1.44269504f
#define CLIP2 (5.0f * LOG2E)      // clip bound in exp2 domain
#define QSCALE (0.125f * LOG2E)   // (1/sqrt(E)) * log2e folded into q

// ---------------------------------------------------------------------------
// attn_fused: per-block = one (n,h) x one key-chunk of 256 keys.
//  - stages K,V chunk into LDS, applying the DxD head projection on the fly
//  - each thread owns 4 queries (projected in registers), loops 256 keys
//  - logits clipped in exp2 domain -> single-pass softmax partials (additive:
//    no max-subtraction needed since logits bounded in [-5,5])
//  - writes partial [o(8), s] per (query, ksplit) for linear combination
// grid = (KS_, N*H), block = 256.
// ---------------------------------------------------------------------------
__global__ __launch_bounds__(256, 4) void attn_fused(
    const float* __restrict__ vals,
    const float* __restrict__ keys,
    const float* __restrict__ qrys,
    const float* __restrict__ Wv,
    const float* __restrict__ Wk,
    const float* __restrict__ Wq,
    float4* __restrict__ po, float* __restrict__ ps)
{
    __shared__ float Ks[KCH * 8];    // [key][d], 8 KB
    __shared__ float Vs[KCH * 8];    // 8 KB
    __shared__ float Wks[64], Wvs[64], Wqs[64];

    const int tid = threadIdx.x;
    const int ks  = blockIdx.x;      // 0..KS_-1
    const int nh  = blockIdx.y;      // n*H + h
    const int n   = nh >> 3;
    const int h   = nh & 7;

    if (tid < 64)        Wks[tid]       = Wk[tid];
    else if (tid < 128)  Wvs[tid - 64]  = Wv[tid - 64];
    else if (tid < 192)  Wqs[tid - 128] = Wq[tid - 128];
    __syncthreads();

    // ---- stage + project this block's 256-key K/V chunk ----
    {
        const int tk = ks * KCH + tid;                       // key index
        const float* kin = keys + (size_t)(n * T_ + tk) * E_ + h * D_;
        const float* vin = vals + (size_t)(n * T_ + tk) * E_ + h * D_;
        float4 k0 = ((const float4*)kin)[0], k1 = ((const float4*)kin)[1];
        float4 v0 = ((const float4*)vin)[0], v1 = ((const float4*)vin)[1];
        float xk[8] = {k0.x,k0.y,k0.z,k0.w,k1.x,k1.y,k1.z,k1.w};
        float xv[8] = {v0.x,v0.y,v0.z,v0.w,v1.x,v1.y,v1.z,v1.w};
        float rk[8], rv[8];
        #pragma unroll
        for (int d = 0; d < 8; ++d) {
            float ak = 0.f, av = 0.f;
            #pragma unroll
            for (int e = 0; e < 8; ++e) {
                ak += xk[e] * Wks[d*8 + e];
                av += xv[e] * Wvs[d*8 + e];
            }
            rk[d] = ak; rv[d] = av;
        }
        ((float4*)&Ks[tid*8])[0] = make_float4(rk[0],rk[1],rk[2],rk[3]);
        ((float4*)&Ks[tid*8])[1] = make_float4(rk[4],rk[5],rk[6],rk[7]);
        ((float4*)&Vs[tid*8])[0] = make_float4(rv[0],rv[1],rv[2],rv[3]);
        ((float4*)&Vs[tid*8])[1] = make_float4(rv[4],rv[5],rv[6],rv[7]);
    }

    // ---- load + project this thread's 4 queries (overlaps staging) ----
    float q[QPT][8], o[QPT][8], sum[QPT];
    #pragma unroll
    for (int j = 0; j < QPT; ++j) {
        const int tq = j * 256 + tid;
        const float* qin = qrys + (size_t)(n * T_ + tq) * E_ + h * D_;
        float4 x0 = ((const float4*)qin)[0], x1 = ((const float4*)qin)[1];
        float x[8] = {x0.x,x0.y,x0.z,x0.w,x1.x,x1.y,x1.z,x1.w};
        #pragma unroll
        for (int d = 0; d < 8; ++d) {
            float a = 0.f;
            #pragma unroll
            for (int e = 0; e < 8; ++e) a += x[e] * Wqs[d*8 + e];
            q[j][d] = a * QSCALE;     // fold scale * log2e
            o[j][d] = 0.f;
        }
        sum[j] = 0.f;
    }
    __syncthreads();

    // ---- main loop: 256 keys, 4 queries per thread ----
    for (int kk = 0; kk < KCH; ++kk) {
        const float4 k0 = ((const float4*)&Ks[kk*8])[0];
        const float4 k1 = ((const float4*)&Ks[kk*8])[1];
        float w[QPT];
        #pragma unroll
        for (int j = 0; j < QPT; ++j) {
            float d = (q[j][0]*k0.x + q[j][1]*k0.y + q[j][2]*k0.z + q[j][3]*k0.w)
                    + (q[j][4]*k1.x + q[j][5]*k1.y + q[j][6]*k1.z + q[j][7]*k1.w);
            d = fminf(fmaxf(d, -CLIP2), CLIP2);   // v_med3
            w[j] = EXP2(d);
            sum[j] += w[j];
        }
        const float4 v0 = ((const float4*)&Vs[kk*8])[0];
        const float4 v1 = ((const float4*)&Vs[kk*8])[1];
        #pragma unroll
        for (int j = 0; j < QPT; ++j) {
            o[j][0] += w[j]*v0.x; o[j][1] += w[j]*v0.y;
            o[j][2] += w[j]*v0.z; o[j][3] += w[j]*v0.w;
            o[j][4] += w[j]*v1.x; o[j][5] += w[j]*v1.y;
            o[j][6] += w[j]*v1.z; o[j][7] += w[j]*v1.w;
        }
    }

    // ---- write partials: record index = ((n*T+t)*H + h)*KS + ks ----
    #pragma unroll
    for (int j = 0; j < QPT; ++j) {
        const int tq = j * 256 + tid;
        const int i  = ((n * T_ + tq) * H_ + h) * KS_ + ks;
        po[2*i]     = make_float4(o[j][0], o[j][1], o[j][2], o[j][3]);
        po[2*i + 1] = make_float4(o[j][4], o[j][5], o[j][6], o[j][7]);
        ps[i] = sum[j];
    }
}

// ---------------------------------------------------------------------------
// combine: sum the KS_ partials per (n,t,h), normalize, write attn [N,T,E].
// one thread per (n,t,h); fully coalesced (thread i reads 128B contiguous).
// ---------------------------------------------------------------------------
__global__ __launch_bounds__(256) void combine_kernel(
    const float4* __restrict__ po, const float* __restrict__ ps,
    float* __restrict__ attn)
{
    const int i = blockIdx.x * 256 + threadIdx.x;   // (n*T+t)*H + h
    float4 a = make_float4(0.f,0.f,0.f,0.f);
    float4 b = make_float4(0.f,0.f,0.f,0.f);
    float s = 0.f;
    #pragma unroll
    for (int ks = 0; ks < KS_; ++ks) {
        const float4 pa = po[(i*KS_ + ks)*2];
        const float4 pb = po[(i*KS_ + ks)*2 + 1];
        a.x += pa.x; a.y += pa.y; a.z += pa.z; a.w += pa.w;
        b.x += pb.x; b.y += pb.y; b.z += pb.z; b.w += pb.w;
        s += ps[i*KS_ + ks];
    }
    const float inv = 1.f / s;
    a.x *= inv; a.y *= inv; a.z *= inv; a.w *= inv;
    b.x *= inv; b.y *= inv; b.z *= inv; b.w *= inv;
    ((float4*)attn)[i*2]     = a;
    ((float4*)attn)[i*2 + 1] = b;
}

// ---------------------------------------------------------------------------
// oproj: out[row,:] = attn[row,:] @ Wo^T + bo.  lane = out-feature eo; each
// lane holds Wo[eo][0..63] in 64 VGPRs (loaded once, amortized over 8 rows);
// x is read wave-uniform (same addr all lanes -> one L2 line) -> zero LDS.
// grid = 1024 x 256 -> 4096 waves x 8 rows = 32768 rows.
// ---------------------------------------------------------------------------
__global__ __launch_bounds__(256) void oproj_kernel(
    const float* __restrict__ attn,
    const float* __restrict__ Wo,
    const float* __restrict__ bo,
    float* __restrict__ out)
{
    const int eo   = threadIdx.x & 63;
    const int wave = (blockIdx.x * 256 + threadIdx.x) >> 6;   // 0..4095
    float4 w[16];
    const float4* wrow = (const float4*)(Wo + eo * 64);
    #pragma unroll
    for (int i = 0; i < 16; ++i) w[i] = wrow[i];
    const float bias = bo[eo];

    #pragma unroll 2
    for (int r = 0; r < 8; ++r) {
        const int row = wave * 8 + r;
        const float4* x = (const float4*)(attn + (size_t)row * 64);
        float acc = bias;
        #pragma unroll
        for (int i = 0; i < 16; ++i) {
            const float4 xv = x[i];
            acc += xv.x*w[i].x + xv.y*w[i].y + xv.z*w[i].z + xv.w*w[i].w;
        }
        out[(size_t)row * 64 + eo] = acc;
    }
}

// ---------------------------------------------------------------------------
extern "C" void kernel_launch(void* const* d_in, const int* in_sizes, int n_in,
                              void* d_out, int out_size, void* d_ws, size_t ws_size,
                              hipStream_t stream)
{
    const float* vals = (const float*)d_in[0];
    const float* keys = (const float*)d_in[1];
    const float* qrys = (const float*)d_in[2];
    const float* Wv   = (const float*)d_in[3];
    const float* Wk   = (const float*)d_in[4];
    const float* Wq   = (const float*)d_in[5];
    const float* Wo   = (const float*)d_in[6];
    const float* bo   = (const float*)d_in[7];

    float* ws = (float*)d_ws;
    // po: N*T*H*KS records x 8 floats = 8,388,608 floats (33.5 MB)
    // ps: N*T*H*KS floats            = 1,048,576 floats ( 4.2 MB)
    // attn: N*T*E                    = 2,097,152 floats ( 8.4 MB)
    float4* po   = (float4*)ws;
    float*  ps   = ws + 8388608;
    float*  attn = ws + 8388608 + 1048576;

    attn_fused<<<dim3(KS_, N_ * H_), 256, 0, stream>>>(
        vals, keys, qrys, Wv, Wk, Wq, po, ps);
    combine_kernel<<<(N_ * T_ * H_) / 256, 256, 0, stream>>>(po, ps, attn);
    oproj_kernel<<<1024, 256, 0, stream>>>(attn, Wo, bo, (float*)d_out);
}